// Round 4
// baseline (984.652 us; speedup 1.0000x reference)
//
#include <hip/hip_runtime.h>
#include <hip/hip_bf16.h>
#include <stdint.h>

typedef __bf16 bf16_t;
typedef __bf16 bf16x8 __attribute__((ext_vector_type(8)));
typedef float f32x4 __attribute__((ext_vector_type(4)));

#define HID 512
#define NRAW 736      // 32 * 23
#define NRAW_PAD 768  // padded N for GEMM3 B-matrix (zero rows 736..767)
#define TAILB 3.0f

// async global->LDS, 16B per lane; LDS dest must be wave-uniform base + lane*16
__device__ __forceinline__ void glds16(const bf16_t* g, bf16_t* s) {
  __builtin_amdgcn_global_load_lds(
      (const __attribute__((address_space(1))) void*)g,
      (__attribute__((address_space(3))) void*)s, 16, 0, 0);
}

__device__ __forceinline__ void split2(float v, bf16_t& hi, bf16_t& lo) {
  hi = (bf16_t)v;
  lo = (bf16_t)(v - (float)hi);
}

// ---------------------------------------------------------------------------
// Dtype detector: flag=1 -> inputs are fp32 (bytes read as bf16 look crazy).
// ---------------------------------------------------------------------------
__global__ void detect_dtype(const void* x, int* flag) {
  __shared__ int s;
  if (threadIdx.x == 0) s = 0;
  __syncthreads();
  const bf16_t* xb = (const bf16_t*)x;
  int cnt = 0;
  for (int j = 0; j < 16; j++) {
    float v = (float)xb[threadIdx.x * 16 + j];
    if (!(v == v) || fabsf(v) > 64.0f) cnt++;
  }
  atomicAdd(&s, cnt);
  __syncthreads();
  if (threadIdx.x == 0) *flag = (s > 64) ? 1 : 0;
}

// ---------------------------------------------------------------------------
// Weight/bias ingest: transpose W (K x N) -> Wt (N x K) as hi/lo bf16 pairs;
// biases -> exact f32. Reads source as fp32 or bf16 per flag.
// ---------------------------------------------------------------------------
__global__ void conv_wb(const void* W1, const void* W2, const void* W3,
                        const void* b1, const void* b2, const void* b3,
                        bf16_t* __restrict__ w1h, bf16_t* __restrict__ w1l,
                        bf16_t* __restrict__ w2h, bf16_t* __restrict__ w2l,
                        bf16_t* __restrict__ w3h, bf16_t* __restrict__ w3l,
                        float* __restrict__ bf1, float* __restrict__ bf2,
                        float* __restrict__ bf3, const int* flagp) {
  const int flag = *flagp;
  auto rd = [&](const void* p, size_t idx) -> float {
    return flag ? ((const float*)p)[idx] : (float)((const bf16_t*)p)[idx];
  };
  int i = blockIdx.x * 256 + threadIdx.x;
  if (i < 512 * 32)  { split2(rd(W1, (size_t)(i & 31) * 512 + (i >> 5)), w1h[i], w1l[i]); return; }
  i -= 512 * 32;
  if (i < 512 * 512) { split2(rd(W2, (size_t)(i & 511) * 512 + (i >> 9)), w2h[i], w2l[i]); return; }
  i -= 512 * 512;
  if (i < NRAW_PAD * 512) {
    int n = i >> 9, k = i & 511;
    float v = (n < NRAW) ? rd(W3, (size_t)k * NRAW + n) : 0.0f;
    split2(v, w3h[i], w3l[i]);
    return;
  }
  i -= NRAW_PAD * 512;
  if (i < 512) { bf1[i] = rd(b1, i); return; }
  i -= 512;
  if (i < 512) { bf2[i] = rd(b2, i); return; }
  i -= 512;
  if (i < NRAW) { bf3[i] = rd(b3, i); }
}

// x ingest: masked half x[:, :32] -> hi/lo bf16 (M x 32 each).
__global__ void convert_x(const void* x, bf16_t* __restrict__ xh,
                          bf16_t* __restrict__ xl, const int* flagp, int n) {
  const int flag = *flagp;
  const int i0 = (blockIdx.x * 256 + threadIdx.x) * 8;
  if (i0 >= n) return;
  const int row = i0 >> 5, col = i0 & 31;
  #pragma unroll
  for (int j = 0; j < 8; j++) {
    const size_t src = (size_t)row * 64 + col + j;
    float v = flag ? ((const float*)x)[src] : (float)((const bf16_t*)x)[src];
    split2(v, xh[i0 + j], xl[i0 + j]);
  }
}

// ---------------------------------------------------------------------------
// Split-precision GEMM: C = act(A @ Bt^T + bias), A = Ah+Al (Mc x KTOT),
// Bt = Bh+Bl (N x KTOT). 3-term MFMA: Ah*Bh + Al*Bh + Ah*Bl.
// 128x128 tile, BK=32, 4 LDS buffers (32 KB). Output: hi/lo pair or fp32.
// ---------------------------------------------------------------------------
template <int KTOT, bool RELU, int NOUT, bool OUTF>
__launch_bounds__(256)
__global__ void gemm_split(const bf16_t* __restrict__ Ah, const bf16_t* __restrict__ Al,
                           const bf16_t* __restrict__ Bh, const bf16_t* __restrict__ Bl,
                           const float* __restrict__ bias,
                           bf16_t* __restrict__ Ch, bf16_t* __restrict__ Cl,
                           float* __restrict__ Cf) {
  __shared__ __align__(16) bf16_t AsH[128 * 32], AsL[128 * 32];
  __shared__ __align__(16) bf16_t BsH[128 * 32], BsL[128 * 32];
  const int t = threadIdx.x;
  const int m0 = blockIdx.x * 128, n0 = blockIdx.y * 128;
  const int row = t >> 2, sc = (t & 3) * 8;   // 64 rows x 64 B per round; LDS off = t*16 B
  const int lane = t & 63, w = t >> 6;
  const int wr = (w >> 1) * 64, wc = (w & 1) * 64;
  const int lm = lane & 15, quad = lane >> 4;

  f32x4 acc[4][4] = {};

  for (int k0 = 0; k0 < KTOT; k0 += 32) {
    #pragma unroll
    for (int r = 0; r < 2; r++) {
      const int gr = r * 64 + row;
      glds16(Ah + (size_t)(m0 + gr) * KTOT + k0 + sc, &AsH[gr * 32 + sc]);
      glds16(Al + (size_t)(m0 + gr) * KTOT + k0 + sc, &AsL[gr * 32 + sc]);
      glds16(Bh + (size_t)(n0 + gr) * KTOT + k0 + sc, &BsH[gr * 32 + sc]);
      glds16(Bl + (size_t)(n0 + gr) * KTOT + k0 + sc, &BsL[gr * 32 + sc]);
    }
    __syncthreads();
    bf16x8 ah[4], al[4], bh[4], bl[4];
    #pragma unroll
    for (int i = 0; i < 4; i++) {
      ah[i] = *(const bf16x8*)&AsH[(wr + i * 16 + lm) * 32 + quad * 8];
      al[i] = *(const bf16x8*)&AsL[(wr + i * 16 + lm) * 32 + quad * 8];
    }
    #pragma unroll
    for (int j = 0; j < 4; j++) {
      bh[j] = *(const bf16x8*)&BsH[(wc + j * 16 + lm) * 32 + quad * 8];
      bl[j] = *(const bf16x8*)&BsL[(wc + j * 16 + lm) * 32 + quad * 8];
    }
    #pragma unroll
    for (int i = 0; i < 4; i++)
      #pragma unroll
      for (int j = 0; j < 4; j++) {
        acc[i][j] = __builtin_amdgcn_mfma_f32_16x16x32_bf16(ah[i], bh[j], acc[i][j], 0, 0, 0);
        acc[i][j] = __builtin_amdgcn_mfma_f32_16x16x32_bf16(al[i], bh[j], acc[i][j], 0, 0, 0);
        acc[i][j] = __builtin_amdgcn_mfma_f32_16x16x32_bf16(ah[i], bl[j], acc[i][j], 0, 0, 0);
      }
    __syncthreads();
  }
  #pragma unroll
  for (int i = 0; i < 4; i++)
    #pragma unroll
    for (int j = 0; j < 4; j++) {
      const int col = n0 + wc + j * 16 + lm;
      const float bv = (col < NOUT) ? bias[col] : 0.0f;
      #pragma unroll
      for (int r = 0; r < 4; r++) {
        const int rowi = m0 + wr + i * 16 + quad * 4 + r;
        float v = acc[i][j][r] + bv;
        if (RELU) v = fmaxf(v, 0.0f);
        if (col < NOUT) {
          if (OUTF) {
            Cf[(size_t)rowi * NOUT + col] = v;
          } else {
            bf16_t hi, lo;
            split2(v, hi, lo);
            Ch[(size_t)rowi * NOUT + col] = hi;
            Cl[(size_t)rowi * NOUT + col] = lo;
          }
        }
      }
    }
}

// ---------------------------------------------------------------------------
// Spline: per (row, channel) RQ-spline transform. 8 rows / block via LDS slab.
// raw is fp32 now. Reads original x per flag; writes out per flag.
// ---------------------------------------------------------------------------
__device__ __forceinline__ float softplusf(float v) {
  return fmaxf(v, 0.0f) + log1pf(__expf(-fabsf(v)));
}

__launch_bounds__(256)
__global__ void spline_kernel(const void* __restrict__ xorig, const float* __restrict__ raw,
                              void* __restrict__ outv, int M, int r0,
                              const int* __restrict__ flagp) {
  __shared__ float sraw[8 * NRAW];
  const int flag = *flagp;
  const int t = threadIdx.x;
  const int lrow0 = blockIdx.x * 8;       // chunk-local row base
  {
    const float4* src = (const float4*)(raw + (size_t)lrow0 * NRAW);
    for (int i = t; i < 8 * NRAW / 4; i += 256) ((float4*)sraw)[i] = src[i];
  }
  __syncthreads();
  const int r = t >> 5, ch = t & 31;
  const int grow = r0 + lrow0 + r;        // global row
  const float* c = &sraw[r * NRAW + ch * 23];

  float xm, xt;
  if (flag) {
    const float* xf = (const float*)xorig + (size_t)grow * 64;
    xm = xf[ch]; xt = xf[32 + ch];
  } else {
    const bf16_t* xb = (const bf16_t*)xorig + (size_t)grow * 64;
    xm = (float)xb[ch]; xt = (float)xb[32 + ch];
  }

  float ew[8], eh[8];
  float mw = c[0], mh = c[8];
  #pragma unroll
  for (int j = 1; j < 8; j++) { mw = fmaxf(mw, c[j]); mh = fmaxf(mh, c[8 + j]); }
  float sew = 0.f, seh = 0.f;
  #pragma unroll
  for (int j = 0; j < 8; j++) {
    ew[j] = __expf(c[j] - mw);      sew += ew[j];
    eh[j] = __expf(c[8 + j] - mh);  seh += eh[j];
  }
  const float wsc = 6.0f / sew, hsc = 6.0f / seh;
  const bool inside = (xt >= -TAILB) && (xt <= TAILB);
  const float xc = fminf(fmaxf(xt, -TAILB + 1e-6f), TAILB - 1e-6f);

  int bin = 0;
  float accw = -TAILB;
  #pragma unroll
  for (int i = 0; i < 8; i++) { accw += ew[i] * wsc; if (accw < xc) bin++; }
  bin = min(bin, 7);

  float wk = 1.f, cwk = -TAILB, hk = 1.f, chk = -TAILB;
  float runw = -TAILB, runh = -TAILB;
  #pragma unroll
  for (int i = 0; i < 8; i++) {
    const float wv = ew[i] * wsc, hv = eh[i] * hsc;
    if (i == bin) { wk = wv; cwk = runw; hk = hv; chk = runh; }
    runw += wv; runh += hv;
  }
  float dkr = 0.f, dk1r = 0.f;
  #pragma unroll
  for (int i = 0; i < 7; i++) {
    const float dv = c[16 + i];
    if (i == bin - 1) dkr = dv;
    if (i == bin)     dk1r = dv;
  }
  const float dk  = (bin == 0) ? 1.0f : softplusf(dkr);
  const float dk1 = (bin == 7) ? 1.0f : softplusf(dk1r);

  float xi = (xc - cwk) / wk;
  xi = fminf(fmaxf(xi, 1e-6f), 1.0f - 1e-6f);
  const float om = 1.0f - xi;
  const float s = hk / wk;
  const float num = hk * (s * xi * xi + dk * xi * om);
  const float den = s + (dk + dk1 - 2.0f * s) * xi * om;
  const float y_in = chk + num / den;
  const float t1 = s * s * (dk1 * xi * xi + 2.0f * s * xi * om + dk * om * om);
  const float ld_in = __logf(t1 + 1e-8f) - __logf(den * den + 1e-8f);

  const float yv = inside ? y_in : xt;
  float ld = inside ? ld_in : 0.0f;
  #pragma unroll
  for (int off = 16; off > 0; off >>= 1) ld += __shfl_down(ld, off, 32);

  if (flag) {
    float* o = (float*)outv;
    o[(size_t)grow * 64 + ch] = xm;
    o[(size_t)grow * 64 + 32 + ch] = yv;
    if (ch == 0) o[(size_t)M * 64 + grow] = ld;
  } else {
    bf16_t* o = (bf16_t*)outv;
    o[(size_t)grow * 64 + ch] = (bf16_t)xm;
    o[(size_t)grow * 64 + 32 + ch] = (bf16_t)yv;
    if (ch == 0) o[(size_t)M * 64 + grow] = (bf16_t)ld;
  }
}

// ---------------------------------------------------------------------------
extern "C" void kernel_launch(void* const* d_in, const int* in_sizes, int n_in,
                              void* d_out, int out_size, void* d_ws, size_t ws_size,
                              hipStream_t stream) {
  const void* x  = d_in[0];
  const void* W1 = d_in[1];
  const void* b1 = d_in[2];
  const void* W2 = d_in[3];
  const void* b2 = d_in[4];
  const void* W3 = d_in[5];
  const void* b3 = d_in[6];
  const int M = in_sizes[0] / 64;  // 131072

  char* ws = (char*)d_ws;
  size_t off = 0;
  auto alloc = [&](size_t bytes) {
    void* p = ws + off;
    off += (bytes + 255) & ~(size_t)255;
    return p;
  };
  int*    flag = (int*)alloc(256);
  float*  bf1  = (float*)alloc(512 * 4);
  float*  bf2  = (float*)alloc(512 * 4);
  float*  bf3  = (float*)alloc(NRAW * 4);
  bf16_t* W1h  = (bf16_t*)alloc((size_t)512 * 32 * 2);
  bf16_t* W1l  = (bf16_t*)alloc((size_t)512 * 32 * 2);
  bf16_t* W2h  = (bf16_t*)alloc((size_t)512 * 512 * 2);
  bf16_t* W2l  = (bf16_t*)alloc((size_t)512 * 512 * 2);
  bf16_t* W3h  = (bf16_t*)alloc((size_t)NRAW_PAD * 512 * 2);
  bf16_t* W3l  = (bf16_t*)alloc((size_t)NRAW_PAD * 512 * 2);
  bf16_t* xh   = (bf16_t*)alloc((size_t)M * 32 * 2);
  bf16_t* xl   = (bf16_t*)alloc((size_t)M * 32 * 2);

  // Chunk so activations fit ws. Per row: union(h1 pair 2048 B, raw f32 2944 B)
  // = 2944 B, plus h2 pair 2048 B.
  const size_t per_row = (size_t)NRAW * 4 + (size_t)HID * 2 * 2;
  size_t avail = (ws_size > off + 4096) ? (ws_size - off - 4096) : 0;
  long rows = (long)(avail / per_row);
  rows -= rows % 128;
  if (rows > M) rows = M;
  if (rows < 128) rows = 128;

  char*   un  = (char*)alloc((size_t)rows * NRAW * 4);   // h1 pair aliases raw
  bf16_t* h1h = (bf16_t*)un;
  bf16_t* h1l = (bf16_t*)(un + (size_t)rows * HID * 2);
  float*  rawf = (float*)un;
  bf16_t* h2h = (bf16_t*)alloc((size_t)rows * HID * 2);
  bf16_t* h2l = (bf16_t*)alloc((size_t)rows * HID * 2);

  detect_dtype<<<1, 256, 0, stream>>>(x, flag);
  conv_wb<<<2631, 256, 0, stream>>>(W1, W2, W3, b1, b2, b3,
                                    W1h, W1l, W2h, W2l, W3h, W3l,
                                    bf1, bf2, bf3, flag);
  convert_x<<<(M * 32 / 8 + 255) / 256, 256, 0, stream>>>(x, xh, xl, flag, M * 32);

  for (int r0 = 0; r0 < M; r0 += (int)rows) {
    const int mc = (int)((M - r0 < rows) ? (M - r0) : rows);
    gemm_split<32, true, HID, false><<<dim3(mc / 128, 4), 256, 0, stream>>>(
        xh + (size_t)r0 * 32, xl + (size_t)r0 * 32, W1h, W1l, bf1, h1h, h1l, nullptr);
    gemm_split<512, true, HID, false><<<dim3(mc / 128, 4), 256, 0, stream>>>(
        h1h, h1l, W2h, W2l, bf2, h2h, h2l, nullptr);
    gemm_split<512, false, NRAW, true><<<dim3(mc / 128, 6), 256, 0, stream>>>(
        h2h, h2l, W3h, W3l, bf3, nullptr, nullptr, rawf);
    spline_kernel<<<mc / 8, 256, 0, stream>>>(x, rawf, d_out, M, r0, flag);
  }
}

// Round 5
// 628.668 us; speedup vs baseline: 1.5662x; 1.5662x over previous
//
#include <hip/hip_runtime.h>
#include <hip/hip_bf16.h>
#include <stdint.h>

typedef __bf16 bf16_t;
typedef _Float16 f16_t;
typedef _Float16 f16x8 __attribute__((ext_vector_type(8)));
typedef float f32x4 __attribute__((ext_vector_type(4)));

#define HID 512
#define NRAW 736      // 32 * 23
#define NRAW_PAD 768  // padded N for GEMM3 B-matrix (zero rows 736..767)
#define TAILB 3.0f

// async global->LDS, 16B per lane; LDS dest must be wave-uniform base + lane*16
__device__ __forceinline__ void glds16(const void* g, void* s) {
  __builtin_amdgcn_global_load_lds(
      (const __attribute__((address_space(1))) void*)g,
      (__attribute__((address_space(3))) void*)s, 16, 0, 0);
}

__device__ __forceinline__ void split2h(float v, f16_t& hi, f16_t& lo) {
  hi = (f16_t)v;
  lo = (f16_t)(v - (float)hi);
}

// ---------------------------------------------------------------------------
// Dtype detector: flag=1 -> inputs are fp32 (bytes read as bf16 look crazy).
// ---------------------------------------------------------------------------
__global__ void detect_dtype(const void* x, int* flag) {
  __shared__ int s;
  if (threadIdx.x == 0) s = 0;
  __syncthreads();
  const bf16_t* xb = (const bf16_t*)x;
  int cnt = 0;
  for (int j = 0; j < 16; j++) {
    float v = (float)xb[threadIdx.x * 16 + j];
    if (!(v == v) || fabsf(v) > 64.0f) cnt++;
  }
  atomicAdd(&s, cnt);
  __syncthreads();
  if (threadIdx.x == 0) *flag = (s > 64) ? 1 : 0;
}

// ---------------------------------------------------------------------------
// Weight/bias ingest: transpose W (K x N) -> Wt (N x K) as f16 hi/lo pairs;
// biases -> exact f32. Reads source as fp32 or bf16 per flag.
// ---------------------------------------------------------------------------
__global__ void conv_wb(const void* W1, const void* W2, const void* W3,
                        const void* b1, const void* b2, const void* b3,
                        f16_t* __restrict__ w1h, f16_t* __restrict__ w1l,
                        f16_t* __restrict__ w2h, f16_t* __restrict__ w2l,
                        f16_t* __restrict__ w3h, f16_t* __restrict__ w3l,
                        float* __restrict__ bf1, float* __restrict__ bf2,
                        float* __restrict__ bf3, const int* flagp) {
  const int flag = *flagp;
  auto rd = [&](const void* p, size_t idx) -> float {
    return flag ? ((const float*)p)[idx] : (float)((const bf16_t*)p)[idx];
  };
  int i = blockIdx.x * 256 + threadIdx.x;
  if (i < 512 * 32)  { split2h(rd(W1, (size_t)(i & 31) * 512 + (i >> 5)), w1h[i], w1l[i]); return; }
  i -= 512 * 32;
  if (i < 512 * 512) { split2h(rd(W2, (size_t)(i & 511) * 512 + (i >> 9)), w2h[i], w2l[i]); return; }
  i -= 512 * 512;
  if (i < NRAW_PAD * 512) {
    int n = i >> 9, k = i & 511;
    float v = (n < NRAW) ? rd(W3, (size_t)k * NRAW + n) : 0.0f;
    split2h(v, w3h[i], w3l[i]);
    return;
  }
  i -= NRAW_PAD * 512;
  if (i < 512) { bf1[i] = rd(b1, i); return; }
  i -= 512;
  if (i < 512) { bf2[i] = rd(b2, i); return; }
  i -= 512;
  if (i < NRAW) { bf3[i] = rd(b3, i); }
}

// x ingest: masked half x[:, :32] -> f16 (M x 32).
__global__ void convert_x(const void* x, f16_t* __restrict__ xf,
                          const int* flagp, int n) {
  const int flag = *flagp;
  const int i0 = (blockIdx.x * 256 + threadIdx.x) * 8;
  if (i0 >= n) return;
  const int row = i0 >> 5, col = i0 & 31;
  #pragma unroll
  for (int j = 0; j < 8; j++) {
    const size_t src = (size_t)row * 64 + col + j;
    float v = flag ? ((const float*)x)[src] : (float)((const bf16_t*)x)[src];
    xf[i0 + j] = (f16_t)v;
  }
}

// ---------------------------------------------------------------------------
// f16 GEMM: C = act(A @ Bt^T + bias). A: Mc x KTOT f16. Bt = Bh+Bl: N x KTOT
// f16 hi/lo (weights, ~22-bit effective). 2-term MFMA: A*Bh + A*Bl.
// 128x128 tile, BK=64 (BK=KTOT if smaller). XOR-swizzled LDS columns
// (swizzle applied on the GLOBAL source column so global_load_lds stays
// lane-linear). blockIdx.x = n-tile (fast dim) for A-tile L2/L3 reuse.
// ---------------------------------------------------------------------------
template <int KTOT, bool RELU, int NOUT>
__launch_bounds__(256)
__global__ void gemm_f16(const f16_t* __restrict__ A, const f16_t* __restrict__ Bh,
                         const f16_t* __restrict__ Bl, const float* __restrict__ bias,
                         f16_t* __restrict__ C) {
  constexpr int BK = (KTOT < 64) ? KTOT : 64;
  constexpr int NCB = BK / 8;         // 16B col-blocks per row
  constexpr int CMASK = NCB - 1;
  constexpr int RPB = (128 * BK * 2) / 4096;   // staging rounds per buffer
  constexpr int RPR = 4096 / (BK * 2);         // rows per round
  __shared__ __align__(16) f16_t As[128 * BK], BsH[128 * BK], BsL[128 * BK];
  const int t = threadIdx.x;
  const int n0 = blockIdx.x * 128, m0 = blockIdx.y * 128;
  const int lrow = (t * 16) / (BK * 2);        // within-round row
  const int lcb  = ((t * 16) % (BK * 2)) / 16; // within-row 16B block index
  const int lane = t & 63, w = t >> 6;
  const int wr = (w >> 1) * 64, wc = (w & 1) * 64;
  const int lm = lane & 15, quad = lane >> 4;

  f32x4 acc[4][4] = {};

  for (int k0 = 0; k0 < KTOT; k0 += BK) {
    #pragma unroll
    for (int r = 0; r < RPB; r++) {
      const int row = r * RPR + lrow;
      const int gc = (lcb ^ (row & CMASK)) * 8;   // swizzled global col
      const int ldst = row * BK + lcb * 8;        // linear LDS dest (= t*16 B)
      glds16(A  + (size_t)(m0 + row) * KTOT + k0 + gc, &As[ldst]);
      glds16(Bh + (size_t)(n0 + row) * KTOT + k0 + gc, &BsH[ldst]);
      glds16(Bl + (size_t)(n0 + row) * KTOT + k0 + gc, &BsL[ldst]);
    }
    __syncthreads();
    #pragma unroll
    for (int ks = 0; ks < BK; ks += 32) {
      const int qb = (ks >> 3) + quad;   // global col-block wanted
      f16x8 af[4], bh[4], bl[4];
      #pragma unroll
      for (int i = 0; i < 4; i++) {
        const int row = wr + i * 16 + lm;
        af[i] = *(const f16x8*)&As[row * BK + ((qb ^ (row & CMASK)) << 3)];
      }
      #pragma unroll
      for (int j = 0; j < 4; j++) {
        const int row = wc + j * 16 + lm;
        const int cc = (qb ^ (row & CMASK)) << 3;
        bh[j] = *(const f16x8*)&BsH[row * BK + cc];
        bl[j] = *(const f16x8*)&BsL[row * BK + cc];
      }
      #pragma unroll
      for (int i = 0; i < 4; i++)
        #pragma unroll
        for (int j = 0; j < 4; j++) {
          acc[i][j] = __builtin_amdgcn_mfma_f32_16x16x32_f16(af[i], bh[j], acc[i][j], 0, 0, 0);
          acc[i][j] = __builtin_amdgcn_mfma_f32_16x16x32_f16(af[i], bl[j], acc[i][j], 0, 0, 0);
        }
    }
    __syncthreads();
  }
  #pragma unroll
  for (int i = 0; i < 4; i++)
    #pragma unroll
    for (int j = 0; j < 4; j++) {
      const int col = n0 + wc + j * 16 + lm;
      const float bv = (col < NOUT) ? bias[col] : 0.0f;
      #pragma unroll
      for (int r = 0; r < 4; r++) {
        const int rowi = m0 + wr + i * 16 + quad * 4 + r;
        float v = acc[i][j][r] + bv;
        if (RELU) v = fmaxf(v, 0.0f);
        if (col < NOUT) C[(size_t)rowi * NOUT + col] = (f16_t)v;
      }
    }
}

// ---------------------------------------------------------------------------
// Spline: per (row, channel) RQ-spline transform. 8 rows / block via LDS slab.
// raw is f16. Reads original x per flag; writes out per flag.
// ---------------------------------------------------------------------------
__device__ __forceinline__ float softplusf(float v) {
  return fmaxf(v, 0.0f) + log1pf(__expf(-fabsf(v)));
}

__launch_bounds__(256)
__global__ void spline_kernel(const void* __restrict__ xorig, const f16_t* __restrict__ raw,
                              void* __restrict__ outv, int M, int r0,
                              const int* __restrict__ flagp) {
  __shared__ float sraw[8 * NRAW];
  const int flag = *flagp;
  const int t = threadIdx.x;
  const int lrow0 = blockIdx.x * 8;       // chunk-local row base
  {
    const f16x8* src = (const f16x8*)(raw + (size_t)lrow0 * NRAW);
    for (int i = t; i < 8 * NRAW / 8; i += 256) {
      f16x8 v = src[i];
      #pragma unroll
      for (int j = 0; j < 8; j++) sraw[i * 8 + j] = (float)v[j];
    }
  }
  __syncthreads();
  const int r = t >> 5, ch = t & 31;
  const int grow = r0 + lrow0 + r;        // global row
  const float* c = &sraw[r * NRAW + ch * 23];

  float xm, xt;
  if (flag) {
    const float* xf = (const float*)xorig + (size_t)grow * 64;
    xm = xf[ch]; xt = xf[32 + ch];
  } else {
    const bf16_t* xb = (const bf16_t*)xorig + (size_t)grow * 64;
    xm = (float)xb[ch]; xt = (float)xb[32 + ch];
  }

  float ew[8], eh[8];
  float mw = c[0], mh = c[8];
  #pragma unroll
  for (int j = 1; j < 8; j++) { mw = fmaxf(mw, c[j]); mh = fmaxf(mh, c[8 + j]); }
  float sew = 0.f, seh = 0.f;
  #pragma unroll
  for (int j = 0; j < 8; j++) {
    ew[j] = __expf(c[j] - mw);      sew += ew[j];
    eh[j] = __expf(c[8 + j] - mh);  seh += eh[j];
  }
  const float wsc = 6.0f / sew, hsc = 6.0f / seh;
  const bool inside = (xt >= -TAILB) && (xt <= TAILB);
  const float xc = fminf(fmaxf(xt, -TAILB + 1e-6f), TAILB - 1e-6f);

  int bin = 0;
  float accw = -TAILB;
  #pragma unroll
  for (int i = 0; i < 8; i++) { accw += ew[i] * wsc; if (accw < xc) bin++; }
  bin = min(bin, 7);

  float wk = 1.f, cwk = -TAILB, hk = 1.f, chk = -TAILB;
  float runw = -TAILB, runh = -TAILB;
  #pragma unroll
  for (int i = 0; i < 8; i++) {
    const float wv = ew[i] * wsc, hv = eh[i] * hsc;
    if (i == bin) { wk = wv; cwk = runw; hk = hv; chk = runh; }
    runw += wv; runh += hv;
  }
  float dkr = 0.f, dk1r = 0.f;
  #pragma unroll
  for (int i = 0; i < 7; i++) {
    const float dv = c[16 + i];
    if (i == bin - 1) dkr = dv;
    if (i == bin)     dk1r = dv;
  }
  const float dk  = (bin == 0) ? 1.0f : softplusf(dkr);
  const float dk1 = (bin == 7) ? 1.0f : softplusf(dk1r);

  float xi = (xc - cwk) / wk;
  xi = fminf(fmaxf(xi, 1e-6f), 1.0f - 1e-6f);
  const float om = 1.0f - xi;
  const float s = hk / wk;
  const float num = hk * (s * xi * xi + dk * xi * om);
  const float den = s + (dk + dk1 - 2.0f * s) * xi * om;
  const float y_in = chk + num / den;
  const float t1 = s * s * (dk1 * xi * xi + 2.0f * s * xi * om + dk * om * om);
  const float ld_in = __logf(t1 + 1e-8f) - __logf(den * den + 1e-8f);

  const float yv = inside ? y_in : xt;
  float ld = inside ? ld_in : 0.0f;
  #pragma unroll
  for (int off = 16; off > 0; off >>= 1) ld += __shfl_down(ld, off, 32);

  if (flag) {
    float* o = (float*)outv;
    o[(size_t)grow * 64 + ch] = xm;
    o[(size_t)grow * 64 + 32 + ch] = yv;
    if (ch == 0) o[(size_t)M * 64 + grow] = ld;
  } else {
    bf16_t* o = (bf16_t*)outv;
    o[(size_t)grow * 64 + ch] = (bf16_t)xm;
    o[(size_t)grow * 64 + 32 + ch] = (bf16_t)yv;
    if (ch == 0) o[(size_t)M * 64 + grow] = (bf16_t)ld;
  }
}

// ---------------------------------------------------------------------------
extern "C" void kernel_launch(void* const* d_in, const int* in_sizes, int n_in,
                              void* d_out, int out_size, void* d_ws, size_t ws_size,
                              hipStream_t stream) {
  const void* x  = d_in[0];
  const void* W1 = d_in[1];
  const void* b1 = d_in[2];
  const void* W2 = d_in[3];
  const void* b2 = d_in[4];
  const void* W3 = d_in[5];
  const void* b3 = d_in[6];
  const int M = in_sizes[0] / 64;  // 131072

  char* ws = (char*)d_ws;
  size_t off = 0;
  auto alloc = [&](size_t bytes) {
    void* p = ws + off;
    off += (bytes + 255) & ~(size_t)255;
    return p;
  };
  int*   flag = (int*)alloc(256);
  float* bf1  = (float*)alloc(512 * 4);
  float* bf2  = (float*)alloc(512 * 4);
  float* bf3  = (float*)alloc(NRAW * 4);
  f16_t* W1h  = (f16_t*)alloc((size_t)512 * 32 * 2);
  f16_t* W1l  = (f16_t*)alloc((size_t)512 * 32 * 2);
  f16_t* W2h  = (f16_t*)alloc((size_t)512 * 512 * 2);
  f16_t* W2l  = (f16_t*)alloc((size_t)512 * 512 * 2);
  f16_t* W3h  = (f16_t*)alloc((size_t)NRAW_PAD * 512 * 2);
  f16_t* W3l  = (f16_t*)alloc((size_t)NRAW_PAD * 512 * 2);
  f16_t* xf   = (f16_t*)alloc((size_t)M * 32 * 2);

  // Chunk so activations fit ws. Per row: union(h1 f16 1024 B, raw f16 1472 B)
  // = 1472 B, plus h2 f16 1024 B.
  const size_t per_row = (size_t)NRAW * 2 + (size_t)HID * 2;
  size_t avail = (ws_size > off + 4096) ? (ws_size - off - 4096) : 0;
  long rows = (long)(avail / per_row);
  rows -= rows % 128;
  if (rows > M) rows = M;
  if (rows < 128) rows = 128;

  char*  un   = (char*)alloc((size_t)rows * NRAW * 2);   // h1 aliases raw
  f16_t* h1   = (f16_t*)un;
  f16_t* rawf = (f16_t*)un;
  f16_t* h2   = (f16_t*)alloc((size_t)rows * HID * 2);

  detect_dtype<<<1, 256, 0, stream>>>(x, flag);
  conv_wb<<<2631, 256, 0, stream>>>(W1, W2, W3, b1, b2, b3,
                                    W1h, W1l, W2h, W2l, W3h, W3l,
                                    bf1, bf2, bf3, flag);
  convert_x<<<(M * 32 / 8 + 255) / 256, 256, 0, stream>>>(x, xf, flag, M * 32);

  for (int r0 = 0; r0 < M; r0 += (int)rows) {
    const int mc = (int)((M - r0 < rows) ? (M - r0) : rows);
    gemm_f16<32, true, HID><<<dim3(4, mc / 128), 256, 0, stream>>>(
        xf + (size_t)r0 * 32, W1h, W1l, bf1, h1);
    gemm_f16<512, true, HID><<<dim3(4, mc / 128), 256, 0, stream>>>(
        h1, W2h, W2l, bf2, h2);
    gemm_f16<512, false, NRAW><<<dim3(6, mc / 128), 256, 0, stream>>>(
        h2, W3h, W3l, bf3, rawf);
    spline_kernel<<<mc / 8, 256, 0, stream>>>(x, rawf, d_out, M, r0, flag);
  }
}

// Round 6
// 487.054 us; speedup vs baseline: 2.0216x; 1.2908x over previous
//
#include <hip/hip_runtime.h>
#include <hip/hip_bf16.h>
#include <stdint.h>

typedef __bf16 bf16_t;
typedef _Float16 f16_t;
typedef _Float16 f16x8 __attribute__((ext_vector_type(8)));
typedef float f32x4 __attribute__((ext_vector_type(4)));

#define HID 512
#define NRAW 736      // 32 * 23
#define NRAW_PAD 768  // padded N for GEMM3 B-matrix (zero rows 736..767)
#define TAILB 3.0f

// async global->LDS, 16B per lane; LDS dest must be wave-uniform base + lane*16
__device__ __forceinline__ void glds16(const void* g, void* s) {
  __builtin_amdgcn_global_load_lds(
      (const __attribute__((address_space(1))) void*)g,
      (__attribute__((address_space(3))) void*)s, 16, 0, 0);
}

// ---------------------------------------------------------------------------
// Dtype detector: flag=1 -> inputs are fp32 (bytes read as bf16 look crazy).
// ---------------------------------------------------------------------------
__global__ void detect_dtype(const void* x, int* flag) {
  __shared__ int s;
  if (threadIdx.x == 0) s = 0;
  __syncthreads();
  const bf16_t* xb = (const bf16_t*)x;
  int cnt = 0;
  for (int j = 0; j < 16; j++) {
    float v = (float)xb[threadIdx.x * 16 + j];
    if (!(v == v) || fabsf(v) > 64.0f) cnt++;
  }
  atomicAdd(&s, cnt);
  __syncthreads();
  if (threadIdx.x == 0) *flag = (s > 64) ? 1 : 0;
}

// ---------------------------------------------------------------------------
// Weight/bias ingest: transpose W (K x N) -> Wt (N x K) as f16; biases -> f32.
// ---------------------------------------------------------------------------
__global__ void conv_wb(const void* W1, const void* W2, const void* W3,
                        const void* b1, const void* b2, const void* b3,
                        f16_t* __restrict__ w1t, f16_t* __restrict__ w2t,
                        f16_t* __restrict__ w3t,
                        float* __restrict__ bf1, float* __restrict__ bf2,
                        float* __restrict__ bf3, const int* flagp) {
  const int flag = *flagp;
  auto rd = [&](const void* p, size_t idx) -> float {
    return flag ? ((const float*)p)[idx] : (float)((const bf16_t*)p)[idx];
  };
  int i = blockIdx.x * 256 + threadIdx.x;
  if (i < 512 * 32)  { w1t[i] = (f16_t)rd(W1, (size_t)(i & 31) * 512 + (i >> 5)); return; }
  i -= 512 * 32;
  if (i < 512 * 512) { w2t[i] = (f16_t)rd(W2, (size_t)(i & 511) * 512 + (i >> 9)); return; }
  i -= 512 * 512;
  if (i < NRAW_PAD * 512) {
    int n = i >> 9, k = i & 511;
    w3t[i] = (n < NRAW) ? (f16_t)rd(W3, (size_t)k * NRAW + n) : (f16_t)0.0f;
    return;
  }
  i -= NRAW_PAD * 512;
  if (i < 512) { bf1[i] = rd(b1, i); return; }
  i -= 512;
  if (i < 512) { bf2[i] = rd(b2, i); return; }
  i -= 512;
  if (i < NRAW) { bf3[i] = rd(b3, i); }
}

// x ingest: masked half x[:, :32] -> f16 (M x 32).
__global__ void convert_x(const void* x, f16_t* __restrict__ xf,
                          const int* flagp, int n) {
  const int flag = *flagp;
  const int i0 = (blockIdx.x * 256 + threadIdx.x) * 8;
  if (i0 >= n) return;
  const int row = i0 >> 5, col = i0 & 31;
  #pragma unroll
  for (int j = 0; j < 8; j++) {
    const size_t src = (size_t)row * 64 + col + j;
    float v = flag ? ((const float*)x)[src] : (float)((const bf16_t*)x)[src];
    xf[i0 + j] = (f16_t)v;
  }
}

// ---------------------------------------------------------------------------
// f16 GEMM: C = act(A @ Bt^T + bias). A: Mc x KTOT f16, Bt: N x KTOT f16.
// 128x128 tile, BK=64 (or KTOT). XOR-swizzled LDS columns (swizzle applied on
// the GLOBAL source column so global_load_lds stays lane-linear).
// XCD-aware 1-D grid: id = s*8 + xcd; (m,n) = ((s/NT)*8+xcd, s%NT) -> the
// NT blocks sharing an A-tile run consecutively on ONE XCD (A hits its L2).
// Requires (m-tiles % 8 == 0): guaranteed by rows % 1024 == 0.
// ---------------------------------------------------------------------------
template <int KTOT, bool RELU, int NOUT, int NT>
__launch_bounds__(256)
__global__ void gemm_f16(const f16_t* __restrict__ A, const f16_t* __restrict__ Bt,
                         const float* __restrict__ bias, f16_t* __restrict__ C) {
  constexpr int BK = (KTOT < 64) ? KTOT : 64;
  constexpr int NCB = BK / 8;         // 16B col-blocks per row
  constexpr int CMASK = NCB - 1;
  constexpr int RPB = (128 * BK * 2) / 4096;   // staging rounds per buffer
  constexpr int RPR = 4096 / (BK * 2);         // rows per round
  __shared__ __align__(16) f16_t As[128 * BK], Bs[128 * BK];
  const int t = threadIdx.x;
  const int id = blockIdx.x;
  const int xcd = id & 7, s = id >> 3;
  const int n0 = (s % NT) * 128;
  const int m0 = ((s / NT) * 8 + xcd) * 128;
  const int lrow = (t * 16) / (BK * 2);        // within-round row
  const int lcb  = ((t * 16) % (BK * 2)) / 16; // within-row 16B block index
  const int lane = t & 63, w = t >> 6;
  const int wr = (w >> 1) * 64, wc = (w & 1) * 64;
  const int lm = lane & 15, quad = lane >> 4;

  f32x4 acc[4][4] = {};

  for (int k0 = 0; k0 < KTOT; k0 += BK) {
    #pragma unroll
    for (int r = 0; r < RPB; r++) {
      const int row = r * RPR + lrow;
      const int gc = (lcb ^ (row & CMASK)) * 8;   // swizzled global col
      const int ldst = row * BK + lcb * 8;        // linear LDS dest (= t*16 B)
      glds16(A  + (size_t)(m0 + row) * KTOT + k0 + gc, &As[ldst]);
      glds16(Bt + (size_t)(n0 + row) * KTOT + k0 + gc, &Bs[ldst]);
    }
    __syncthreads();
    #pragma unroll
    for (int ks = 0; ks < BK; ks += 32) {
      const int qb = (ks >> 3) + quad;   // global col-block wanted
      f16x8 af[4], bf[4];
      #pragma unroll
      for (int i = 0; i < 4; i++) {
        const int row = wr + i * 16 + lm;
        af[i] = *(const f16x8*)&As[row * BK + ((qb ^ (row & CMASK)) << 3)];
      }
      #pragma unroll
      for (int j = 0; j < 4; j++) {
        const int row = wc + j * 16 + lm;
        bf[j] = *(const f16x8*)&Bs[row * BK + ((qb ^ (row & CMASK)) << 3)];
      }
      #pragma unroll
      for (int i = 0; i < 4; i++)
        #pragma unroll
        for (int j = 0; j < 4; j++)
          acc[i][j] = __builtin_amdgcn_mfma_f32_16x16x32_f16(af[i], bf[j], acc[i][j], 0, 0, 0);
    }
    __syncthreads();
  }
  #pragma unroll
  for (int i = 0; i < 4; i++)
    #pragma unroll
    for (int j = 0; j < 4; j++) {
      const int col = n0 + wc + j * 16 + lm;
      const float bv = (col < NOUT) ? bias[col] : 0.0f;
      #pragma unroll
      for (int r = 0; r < 4; r++) {
        const int rowi = m0 + wr + i * 16 + quad * 4 + r;
        float v = acc[i][j][r] + bv;
        if (RELU) v = fmaxf(v, 0.0f);
        if (col < NOUT) C[(size_t)rowi * NOUT + col] = (f16_t)v;
      }
    }
}

// ---------------------------------------------------------------------------
// Spline: per (row, channel) RQ-spline transform. 8 rows / block via LDS slab.
// ---------------------------------------------------------------------------
__device__ __forceinline__ float softplusf(float v) {
  return fmaxf(v, 0.0f) + log1pf(__expf(-fabsf(v)));
}

__launch_bounds__(256)
__global__ void spline_kernel(const void* __restrict__ xorig, const f16_t* __restrict__ raw,
                              void* __restrict__ outv, int M, int r0,
                              const int* __restrict__ flagp) {
  __shared__ float sraw[8 * NRAW];
  const int flag = *flagp;
  const int t = threadIdx.x;
  const int lrow0 = blockIdx.x * 8;       // chunk-local row base
  {
    const f16x8* src = (const f16x8*)(raw + (size_t)lrow0 * NRAW);
    for (int i = t; i < 8 * NRAW / 8; i += 256) {
      f16x8 v = src[i];
      #pragma unroll
      for (int j = 0; j < 8; j++) sraw[i * 8 + j] = (float)v[j];
    }
  }
  __syncthreads();
  const int r = t >> 5, ch = t & 31;
  const int grow = r0 + lrow0 + r;        // global row
  const float* c = &sraw[r * NRAW + ch * 23];

  float xm, xt;
  if (flag) {
    const float* xf = (const float*)xorig + (size_t)grow * 64;
    xm = xf[ch]; xt = xf[32 + ch];
  } else {
    const bf16_t* xb = (const bf16_t*)xorig + (size_t)grow * 64;
    xm = (float)xb[ch]; xt = (float)xb[32 + ch];
  }

  float ew[8], eh[8];
  float mw = c[0], mh = c[8];
  #pragma unroll
  for (int j = 1; j < 8; j++) { mw = fmaxf(mw, c[j]); mh = fmaxf(mh, c[8 + j]); }
  float sew = 0.f, seh = 0.f;
  #pragma unroll
  for (int j = 0; j < 8; j++) {
    ew[j] = __expf(c[j] - mw);      sew += ew[j];
    eh[j] = __expf(c[8 + j] - mh);  seh += eh[j];
  }
  const float wsc = 6.0f / sew, hsc = 6.0f / seh;
  const bool inside = (xt >= -TAILB) && (xt <= TAILB);
  const float xc = fminf(fmaxf(xt, -TAILB + 1e-6f), TAILB - 1e-6f);

  int bin = 0;
  float accw = -TAILB;
  #pragma unroll
  for (int i = 0; i < 8; i++) { accw += ew[i] * wsc; if (accw < xc) bin++; }
  bin = min(bin, 7);

  float wk = 1.f, cwk = -TAILB, hk = 1.f, chk = -TAILB;
  float runw = -TAILB, runh = -TAILB;
  #pragma unroll
  for (int i = 0; i < 8; i++) {
    const float wv = ew[i] * wsc, hv = eh[i] * hsc;
    if (i == bin) { wk = wv; cwk = runw; hk = hv; chk = runh; }
    runw += wv; runh += hv;
  }
  float dkr = 0.f, dk1r = 0.f;
  #pragma unroll
  for (int i = 0; i < 7; i++) {
    const float dv = c[16 + i];
    if (i == bin - 1) dkr = dv;
    if (i == bin)     dk1r = dv;
  }
  const float dk  = (bin == 0) ? 1.0f : softplusf(dkr);
  const float dk1 = (bin == 7) ? 1.0f : softplusf(dk1r);

  float xi = (xc - cwk) / wk;
  xi = fminf(fmaxf(xi, 1e-6f), 1.0f - 1e-6f);
  const float om = 1.0f - xi;
  const float s = hk / wk;
  const float num = hk * (s * xi * xi + dk * xi * om);
  const float den = s + (dk + dk1 - 2.0f * s) * xi * om;
  const float y_in = chk + num / den;
  const float t1 = s * s * (dk1 * xi * xi + 2.0f * s * xi * om + dk * om * om);
  const float ld_in = __logf(t1 + 1e-8f) - __logf(den * den + 1e-8f);

  const float yv = inside ? y_in : xt;
  float ld = inside ? ld_in : 0.0f;
  #pragma unroll
  for (int off = 16; off > 0; off >>= 1) ld += __shfl_down(ld, off, 32);

  if (flag) {
    float* o = (float*)outv;
    o[(size_t)grow * 64 + ch] = xm;
    o[(size_t)grow * 64 + 32 + ch] = yv;
    if (ch == 0) o[(size_t)M * 64 + grow] = ld;
  } else {
    bf16_t* o = (bf16_t*)outv;
    o[(size_t)grow * 64 + ch] = (bf16_t)xm;
    o[(size_t)grow * 64 + 32 + ch] = (bf16_t)yv;
    if (ch == 0) o[(size_t)M * 64 + grow] = (bf16_t)ld;
  }
}

// ---------------------------------------------------------------------------
extern "C" void kernel_launch(void* const* d_in, const int* in_sizes, int n_in,
                              void* d_out, int out_size, void* d_ws, size_t ws_size,
                              hipStream_t stream) {
  const void* x  = d_in[0];
  const void* W1 = d_in[1];
  const void* b1 = d_in[2];
  const void* W2 = d_in[3];
  const void* b2 = d_in[4];
  const void* W3 = d_in[5];
  const void* b3 = d_in[6];
  const int M = in_sizes[0] / 64;  // 131072

  char* ws = (char*)d_ws;
  size_t off = 0;
  auto alloc = [&](size_t bytes) {
    void* p = ws + off;
    off += (bytes + 255) & ~(size_t)255;
    return p;
  };
  int*   flag = (int*)alloc(256);
  float* bf1  = (float*)alloc(512 * 4);
  float* bf2  = (float*)alloc(512 * 4);
  float* bf3  = (float*)alloc(NRAW * 4);
  f16_t* W1t  = (f16_t*)alloc((size_t)512 * 32 * 2);
  f16_t* W2t  = (f16_t*)alloc((size_t)512 * 512 * 2);
  f16_t* W3t  = (f16_t*)alloc((size_t)NRAW_PAD * 512 * 2);
  f16_t* xf   = (f16_t*)alloc((size_t)M * 32 * 2);

  // Chunk so activations fit ws. Per row: union(h1 f16 1024 B, raw f16 1472 B)
  // = 1472 B, plus h2 f16 1024 B. rows % 1024 == 0 (XCD swizzle needs mt % 8).
  const size_t per_row = (size_t)NRAW * 2 + (size_t)HID * 2;
  size_t avail = (ws_size > off + 4096) ? (ws_size - off - 4096) : 0;
  long rows = (long)(avail / per_row);
  rows -= rows % 1024;
  if (rows > M) rows = M;
  if (rows < 1024) rows = 1024;

  char*  un   = (char*)alloc((size_t)rows * NRAW * 2);   // h1 aliases raw
  f16_t* h1   = (f16_t*)un;
  f16_t* rawf = (f16_t*)un;
  f16_t* h2   = (f16_t*)alloc((size_t)rows * HID * 2);

  detect_dtype<<<1, 256, 0, stream>>>(x, flag);
  conv_wb<<<2631, 256, 0, stream>>>(W1, W2, W3, b1, b2, b3,
                                    W1t, W2t, W3t, bf1, bf2, bf3, flag);
  convert_x<<<(M * 32 / 8 + 255) / 256, 256, 0, stream>>>(x, xf, flag, M * 32);

  for (int r0 = 0; r0 < M; r0 += (int)rows) {
    const int mc = (int)((M - r0 < rows) ? (M - r0) : rows);
    const int mt = mc / 128;
    gemm_f16<32, true, HID, 4><<<mt * 4, 256, 0, stream>>>(
        xf + (size_t)r0 * 32, W1t, bf1, h1);
    gemm_f16<512, true, HID, 4><<<mt * 4, 256, 0, stream>>>(
        h1, W2t, bf2, h2);
    gemm_f16<512, false, NRAW, 6><<<mt * 6, 256, 0, stream>>>(
        h2, W3t, bf3, rawf);
    spline_kernel<<<mc / 8, 256, 0, stream>>>(x, rawf, d_out, M, r0, flag);
  }
}

// Round 7
// 405.301 us; speedup vs baseline: 2.4294x; 1.2017x over previous
//
#include <hip/hip_runtime.h>
#include <hip/hip_bf16.h>
#include <stdint.h>

typedef __bf16 bf16_t;
typedef _Float16 f16_t;
typedef _Float16 f16x8 __attribute__((ext_vector_type(8)));
typedef float f32x4 __attribute__((ext_vector_type(4)));

#define HID 512
#define NRAW 736      // 32 * 23
#define NRAW_PAD 768  // padded N/stride for GEMM3 output
#define TAILB 3.0f

// async global->LDS, 16B per lane; LDS dest must be wave-uniform base + lane*16
__device__ __forceinline__ void glds16(const void* g, void* s) {
  __builtin_amdgcn_global_load_lds(
      (const __attribute__((address_space(1))) void*)g,
      (__attribute__((address_space(3))) void*)s, 16, 0, 0);
}

// ---------------------------------------------------------------------------
// Dtype detector: flag=1 -> inputs are fp32 (bytes read as bf16 look crazy).
// ---------------------------------------------------------------------------
__global__ void detect_dtype(const void* x, int* flag) {
  __shared__ int s;
  if (threadIdx.x == 0) s = 0;
  __syncthreads();
  const bf16_t* xb = (const bf16_t*)x;
  int cnt = 0;
  for (int j = 0; j < 16; j++) {
    float v = (float)xb[threadIdx.x * 16 + j];
    if (!(v == v) || fabsf(v) > 64.0f) cnt++;
  }
  atomicAdd(&s, cnt);
  __syncthreads();
  if (threadIdx.x == 0) *flag = (s > 64) ? 1 : 0;
}

// ---------------------------------------------------------------------------
// Weight/bias ingest: transpose W (K x N) -> Wt (N x K) as f16; biases -> f32
// (b3 zero-padded to 768).
// ---------------------------------------------------------------------------
__global__ void conv_wb(const void* W1, const void* W2, const void* W3,
                        const void* b1, const void* b2, const void* b3,
                        f16_t* __restrict__ w1t, f16_t* __restrict__ w2t,
                        f16_t* __restrict__ w3t,
                        float* __restrict__ bf1, float* __restrict__ bf2,
                        float* __restrict__ bf3, const int* flagp) {
  const int flag = *flagp;
  auto rd = [&](const void* p, size_t idx) -> float {
    return flag ? ((const float*)p)[idx] : (float)((const bf16_t*)p)[idx];
  };
  int i = blockIdx.x * 256 + threadIdx.x;
  if (i < 512 * 32)  { w1t[i] = (f16_t)rd(W1, (size_t)(i & 31) * 512 + (i >> 5)); return; }
  i -= 512 * 32;
  if (i < 512 * 512) { w2t[i] = (f16_t)rd(W2, (size_t)(i & 511) * 512 + (i >> 9)); return; }
  i -= 512 * 512;
  if (i < NRAW_PAD * 512) {
    int n = i >> 9, k = i & 511;
    w3t[i] = (n < NRAW) ? (f16_t)rd(W3, (size_t)k * NRAW + n) : (f16_t)0.0f;
    return;
  }
  i -= NRAW_PAD * 512;
  if (i < 512) { bf1[i] = rd(b1, i); return; }
  i -= 512;
  if (i < 512) { bf2[i] = rd(b2, i); return; }
  i -= 512;
  if (i < NRAW_PAD) { bf3[i] = (i < NRAW) ? rd(b3, i) : 0.0f; }
}

// x ingest: masked half x[:, :32] -> f16 (M x 32).
__global__ void convert_x(const void* x, f16_t* __restrict__ xf,
                          const int* flagp, int n) {
  const int flag = *flagp;
  const int i0 = (blockIdx.x * 256 + threadIdx.x) * 8;
  if (i0 >= n) return;
  const int row = i0 >> 5, col = i0 & 31;
  #pragma unroll
  for (int j = 0; j < 8; j++) {
    const size_t src = (size_t)row * 64 + col + j;
    float v = flag ? ((const float*)x)[src] : (float)((const bf16_t*)x)[src];
    xf[i0 + j] = (f16_t)v;
  }
}

// ---------------------------------------------------------------------------
// f16 GEMM: C = act(A @ Bt^T + bias). A: Mc x KTOT f16, Bt: (NT*128) x KTOT.
// 128x128 tile, BK=64 (or KTOT). XOR-swizzled LDS columns, swizzle applied on
// the GLOBAL source column so global_load_lds stays lane-linear. Fragment LDS
// pointers fully hoisted out of the K-loop (k0-invariant). Unconditional
// epilogue stores at stride OS (GEMM3 pads to 768: W3t pad rows + bias pad
// are zero). XCD-aware 1-D grid: the NT blocks sharing an A-tile run
// consecutively on ONE XCD. Requires m-tiles % 8 == 0 (rows % 1024 == 0).
// ---------------------------------------------------------------------------
template <int KTOT, bool RELU, int OS, int NT>
__launch_bounds__(256)
__global__ void gemm_f16(const f16_t* __restrict__ A, const f16_t* __restrict__ Bt,
                         const float* __restrict__ bias, f16_t* __restrict__ C) {
  constexpr int BK = (KTOT < 64) ? KTOT : 64;
  constexpr int NCB = BK / 8;         // 16B col-blocks per row
  constexpr int CMASK = NCB - 1;
  constexpr int NKS = BK / 32;        // MFMA k-steps per buffer
  constexpr int RPB = (128 * BK * 2) / 4096;   // staging rounds per buffer
  constexpr int RPR = 4096 / (BK * 2);         // rows per round
  __shared__ __align__(16) f16_t As[128 * BK], Bs[128 * BK];
  const int t = threadIdx.x;
  const int id = blockIdx.x;
  const int xcd = id & 7, s = id >> 3;
  const int n0 = (s % NT) * 128;
  const int m0 = ((s / NT) * 8 + xcd) * 128;
  const int lrow = (t * 16) / (BK * 2);        // within-round staging row
  const int lcb  = ((t * 16) % (BK * 2)) / 16; // within-row 16B block index
  const int lane = t & 63, w = t >> 6;
  const int wr = (w >> 1) * 64, wc = (w & 1) * 64;
  const int lm = lane & 15, quad = lane >> 4;

  // Hoisted k0-invariant pointers -----------------------------------------
  const f16_t* ga[RPB];
  const f16_t* gb[RPB];
  f16_t* lda[RPB];
  f16_t* ldb[RPB];
  #pragma unroll
  for (int r = 0; r < RPB; r++) {
    const int row = r * RPR + lrow;
    const int gc = (lcb ^ (row & CMASK)) * 8;   // swizzled global col
    ga[r] = A + (size_t)(m0 + row) * KTOT + gc;
    gb[r] = Bt + (size_t)(n0 + row) * KTOT + gc;
    lda[r] = &As[row * BK + lcb * 8];           // lane-linear LDS dest
    ldb[r] = &Bs[row * BK + lcb * 8];
  }
  const f16x8* ap[4][NKS];
  const f16x8* bp[4][NKS];
  #pragma unroll
  for (int i = 0; i < 4; i++) {
    const int ra = wr + i * 16 + lm, rb = wc + i * 16 + lm;
    #pragma unroll
    for (int ksi = 0; ksi < NKS; ksi++) {
      const int qb = ksi * 4 + quad;
      ap[i][ksi] = (const f16x8*)&As[ra * BK + ((qb ^ (ra & CMASK)) << 3)];
      bp[i][ksi] = (const f16x8*)&Bs[rb * BK + ((qb ^ (rb & CMASK)) << 3)];
    }
  }

  f32x4 acc[4][4] = {};

  #pragma unroll
  for (int k0 = 0; k0 < KTOT; k0 += BK) {
    #pragma unroll
    for (int r = 0; r < RPB; r++) {
      glds16(ga[r] + k0, lda[r]);
      glds16(gb[r] + k0, ldb[r]);
    }
    __syncthreads();
    #pragma unroll
    for (int ksi = 0; ksi < NKS; ksi++) {
      f16x8 af[4], bf[4];
      #pragma unroll
      for (int i = 0; i < 4; i++) af[i] = *ap[i][ksi];
      #pragma unroll
      for (int j = 0; j < 4; j++) bf[j] = *bp[j][ksi];
      #pragma unroll
      for (int i = 0; i < 4; i++)
        #pragma unroll
        for (int j = 0; j < 4; j++)
          acc[i][j] = __builtin_amdgcn_mfma_f32_16x16x32_f16(af[i], bf[j], acc[i][j], 0, 0, 0);
    }
    __syncthreads();
  }
  #pragma unroll
  for (int i = 0; i < 4; i++)
    #pragma unroll
    for (int j = 0; j < 4; j++) {
      const int col = n0 + wc + j * 16 + lm;
      const float bv = bias[col];
      #pragma unroll
      for (int r = 0; r < 4; r++) {
        const int rowi = m0 + wr + i * 16 + quad * 4 + r;
        float v = acc[i][j][r] + bv;
        if (RELU) v = fmaxf(v, 0.0f);
        C[(size_t)rowi * OS + col] = (f16_t)v;
      }
    }
}

// ---------------------------------------------------------------------------
// Spline: per (row, channel) RQ-spline transform. 8 rows / block via LDS slab.
// raw is f16 with stride NRAW_PAD.
// ---------------------------------------------------------------------------
__device__ __forceinline__ float softplusf(float v) {
  return fmaxf(v, 0.0f) + log1pf(__expf(-fabsf(v)));
}

__launch_bounds__(256)
__global__ void spline_kernel(const void* __restrict__ xorig, const f16_t* __restrict__ raw,
                              void* __restrict__ outv, int M, int r0,
                              const int* __restrict__ flagp) {
  __shared__ float sraw[8 * NRAW_PAD];
  const int flag = *flagp;
  const int t = threadIdx.x;
  const int lrow0 = blockIdx.x * 8;       // chunk-local row base
  {
    const f16x8* src = (const f16x8*)(raw + (size_t)lrow0 * NRAW_PAD);
    for (int i = t; i < 8 * NRAW_PAD / 8; i += 256) {
      f16x8 v = src[i];
      #pragma unroll
      for (int j = 0; j < 8; j++) sraw[i * 8 + j] = (float)v[j];
    }
  }
  __syncthreads();
  const int r = t >> 5, ch = t & 31;
  const int grow = r0 + lrow0 + r;        // global row
  const float* c = &sraw[r * NRAW_PAD + ch * 23];

  float xm, xt;
  if (flag) {
    const float* xf = (const float*)xorig + (size_t)grow * 64;
    xm = xf[ch]; xt = xf[32 + ch];
  } else {
    const bf16_t* xb = (const bf16_t*)xorig + (size_t)grow * 64;
    xm = (float)xb[ch]; xt = (float)xb[32 + ch];
  }

  float ew[8], eh[8];
  float mw = c[0], mh = c[8];
  #pragma unroll
  for (int j = 1; j < 8; j++) { mw = fmaxf(mw, c[j]); mh = fmaxf(mh, c[8 + j]); }
  float sew = 0.f, seh = 0.f;
  #pragma unroll
  for (int j = 0; j < 8; j++) {
    ew[j] = __expf(c[j] - mw);      sew += ew[j];
    eh[j] = __expf(c[8 + j] - mh);  seh += eh[j];
  }
  const float wsc = 6.0f / sew, hsc = 6.0f / seh;
  const bool inside = (xt >= -TAILB) && (xt <= TAILB);
  const float xc = fminf(fmaxf(xt, -TAILB + 1e-6f), TAILB - 1e-6f);

  int bin = 0;
  float accw = -TAILB;
  #pragma unroll
  for (int i = 0; i < 8; i++) { accw += ew[i] * wsc; if (accw < xc) bin++; }
  bin = min(bin, 7);

  float wk = 1.f, cwk = -TAILB, hk = 1.f, chk = -TAILB;
  float runw = -TAILB, runh = -TAILB;
  #pragma unroll
  for (int i = 0; i < 8; i++) {
    const float wv = ew[i] * wsc, hv = eh[i] * hsc;
    if (i == bin) { wk = wv; cwk = runw; hk = hv; chk = runh; }
    runw += wv; runh += hv;
  }
  float dkr = 0.f, dk1r = 0.f;
  #pragma unroll
  for (int i = 0; i < 7; i++) {
    const float dv = c[16 + i];
    if (i == bin - 1) dkr = dv;
    if (i == bin)     dk1r = dv;
  }
  const float dk  = (bin == 0) ? 1.0f : softplusf(dkr);
  const float dk1 = (bin == 7) ? 1.0f : softplusf(dk1r);

  float xi = (xc - cwk) / wk;
  xi = fminf(fmaxf(xi, 1e-6f), 1.0f - 1e-6f);
  const float om = 1.0f - xi;
  const float s = hk / wk;
  const float num = hk * (s * xi * xi + dk * xi * om);
  const float den = s + (dk + dk1 - 2.0f * s) * xi * om;
  const float y_in = chk + num / den;
  const float t1 = s * s * (dk1 * xi * xi + 2.0f * s * xi * om + dk * om * om);
  const float ld_in = __logf(t1 + 1e-8f) - __logf(den * den + 1e-8f);

  const float yv = inside ? y_in : xt;
  float ld = inside ? ld_in : 0.0f;
  #pragma unroll
  for (int off = 16; off > 0; off >>= 1) ld += __shfl_down(ld, off, 32);

  if (flag) {
    float* o = (float*)outv;
    o[(size_t)grow * 64 + ch] = xm;
    o[(size_t)grow * 64 + 32 + ch] = yv;
    if (ch == 0) o[(size_t)M * 64 + grow] = ld;
  } else {
    bf16_t* o = (bf16_t*)outv;
    o[(size_t)grow * 64 + ch] = (bf16_t)xm;
    o[(size_t)grow * 64 + 32 + ch] = (bf16_t)yv;
    if (ch == 0) o[(size_t)M * 64 + grow] = (bf16_t)ld;
  }
}

// ---------------------------------------------------------------------------
extern "C" void kernel_launch(void* const* d_in, const int* in_sizes, int n_in,
                              void* d_out, int out_size, void* d_ws, size_t ws_size,
                              hipStream_t stream) {
  const void* x  = d_in[0];
  const void* W1 = d_in[1];
  const void* b1 = d_in[2];
  const void* W2 = d_in[3];
  const void* b2 = d_in[4];
  const void* W3 = d_in[5];
  const void* b3 = d_in[6];
  const int M = in_sizes[0] / 64;  // 131072

  char* ws = (char*)d_ws;
  size_t off = 0;
  auto alloc = [&](size_t bytes) {
    void* p = ws + off;
    off += (bytes + 255) & ~(size_t)255;
    return p;
  };
  int*   flag = (int*)alloc(256);
  float* bf1  = (float*)alloc(512 * 4);
  float* bf2  = (float*)alloc(512 * 4);
  float* bf3  = (float*)alloc(NRAW_PAD * 4);
  f16_t* W1t  = (f16_t*)alloc((size_t)512 * 32 * 2);
  f16_t* W2t  = (f16_t*)alloc((size_t)512 * 512 * 2);
  f16_t* W3t  = (f16_t*)alloc((size_t)NRAW_PAD * 512 * 2);
  f16_t* xf   = (f16_t*)alloc((size_t)M * 32 * 2);

  // Chunk so activations fit ws. Per row: union(h1 1024 B, raw 1536 B) = 1536,
  // plus h2 1024 B. rows % 1024 == 0 (XCD swizzle needs m-tiles % 8).
  const size_t per_row = (size_t)NRAW_PAD * 2 + (size_t)HID * 2;
  size_t avail = (ws_size > off + 4096) ? (ws_size - off - 4096) : 0;
  long rows = (long)(avail / per_row);
  rows -= rows % 1024;
  if (rows > M) rows = M;
  if (rows < 1024) rows = 1024;

  char*  un   = (char*)alloc((size_t)rows * NRAW_PAD * 2);   // h1 aliases raw
  f16_t* h1   = (f16_t*)un;
  f16_t* rawf = (f16_t*)un;
  f16_t* h2   = (f16_t*)alloc((size_t)rows * HID * 2);

  detect_dtype<<<1, 256, 0, stream>>>(x, flag);
  conv_wb<<<2631, 256, 0, stream>>>(W1, W2, W3, b1, b2, b3,
                                    W1t, W2t, W3t, bf1, bf2, bf3, flag);
  convert_x<<<(M * 32 / 8 + 255) / 256, 256, 0, stream>>>(x, xf, flag, M * 32);

  for (int r0 = 0; r0 < M; r0 += (int)rows) {
    const int mc = (int)((M - r0 < rows) ? (M - r0) : rows);
    const int mt = mc / 128;
    gemm_f16<32, true, HID, 4><<<mt * 4, 256, 0, stream>>>(
        xf + (size_t)r0 * 32, W1t, bf1, h1);
    gemm_f16<512, true, HID, 4><<<mt * 4, 256, 0, stream>>>(
        h1, W2t, bf2, h2);
    gemm_f16<512, false, NRAW_PAD, 6><<<mt * 6, 256, 0, stream>>>(
        h2, W3t, bf3, rawf);
    spline_kernel<<<mc / 8, 256, 0, stream>>>(x, rawf, d_out, M, r0, flag);
  }
}